// Round 10
// baseline (178.213 us; speedup 1.0000x reference)
//
#include <hip/hip_runtime.h>
#include <math.h>

#define DIN 512
#define DOUT 256
#define NEG_SLOPE 0.01f

typedef __attribute__((ext_vector_type(8))) short bf16x8;
typedef __attribute__((ext_vector_type(4))) float f32x4;
typedef __attribute__((ext_vector_type(4))) unsigned int u32x4;

__device__ __forceinline__ unsigned short f2bf(float f) {
    unsigned int u = __float_as_uint(f);
    unsigned int r = (u + 0x7FFFu + ((u >> 16) & 1u)) >> 16;
    return (unsigned short)r;
}
__device__ __forceinline__ float bf2f(unsigned short u) {
    return __uint_as_float(((unsigned int)u) << 16);
}
__device__ __forceinline__ unsigned int cvtpk(float lo, float hi) {
    unsigned int r;
    asm("v_cvt_pk_bf16_f32 %0, %1, %2" : "=v"(r) : "v"(lo), "v"(hi));
    return r;
}

// ---------------- prep: Bpack = bf16(W) in MFMA fragment order; zero deg/s_src/s_dst --
// Fragment f = ks*16 + cg (ks: K-step of 32, cg: 16-col group). Lane (g,l15) of frag f
// holds W[k = ks*32+g*8 .. +8][col = cg*16+l15]. Stored at Bpack[(f*64+lane)*8].
__global__ void prep(const float* __restrict__ W, unsigned short* __restrict__ Bp,
                     int* __restrict__ deg, float* __restrict__ s_src,
                     float* __restrict__ s_dst, int N) {
    int t = blockIdx.x * blockDim.x + threadIdx.x;
    if (t < (DIN / 32) * (DOUT / 16) * 64) {  // 16384
        int lane = t & 63;
        int cg = (t >> 6) & 15;
        int ks = t >> 10;
        int l15 = lane & 15, g = lane >> 4;
        int col = cg * 16 + l15;
        int k0 = ks * 32 + g * 8;
        ushort4 lo, hi;
        lo.x = f2bf(W[(size_t)(k0 + 0) * DOUT + col]);
        lo.y = f2bf(W[(size_t)(k0 + 1) * DOUT + col]);
        lo.z = f2bf(W[(size_t)(k0 + 2) * DOUT + col]);
        lo.w = f2bf(W[(size_t)(k0 + 3) * DOUT + col]);
        hi.x = f2bf(W[(size_t)(k0 + 4) * DOUT + col]);
        hi.y = f2bf(W[(size_t)(k0 + 5) * DOUT + col]);
        hi.z = f2bf(W[(size_t)(k0 + 6) * DOUT + col]);
        hi.w = f2bf(W[(size_t)(k0 + 7) * DOUT + col]);
        *(ushort4*)(Bp + (size_t)t * 8) = lo;
        *(ushort4*)(Bp + (size_t)t * 8 + 4) = hi;
    }
    if (t < N) { deg[t] = 0; s_src[t] = 0.f; s_dst[t] = 0.f; }
}

// ---------------- GEMM: hb = bf16( x @ W ), fused s_src/s_dst dots ----------
// One wave per block, 32 rows x 256 cols, ~400 VGPRs (launch_bounds 64,1).
// Phase 1: ALL A loaded up front (64 independent HBM loads -> deep MLP), converted
// to 32 bf16x8. Phase 2: K-loop with explicit double-buffered B prefetch (L2-hot
// Bpack fragments) -- issue ks+1's 16 loads, then 32 MFMAs of ks. No LDS/barriers.
__global__ __launch_bounds__(64, 1) void gemm_k(const float* __restrict__ x,
                                                const unsigned short* __restrict__ Bp,
                                                unsigned short* __restrict__ hb,
                                                const float* __restrict__ av,
                                                float* __restrict__ s_src,
                                                float* __restrict__ s_dst, int M) {
    const int lane = threadIdx.x;   // one wave per block
    const int l15 = lane & 15;
    const int g = lane >> 4;
    const int m0 = blockIdx.x * 32;

    int r0 = min(m0 + l15, M - 1);
    int r1 = min(m0 + 16 + l15, M - 1);
    const float* pA0 = x + (size_t)r0 * DIN + g * 8;
    const float* pA1 = x + (size_t)r1 * DIN + g * 8;
    const unsigned short* pB = Bp + (size_t)lane * 8;

    // ---- Phase 1: load all A, convert to bf16 fragments ----
    bf16x8 af0[16], af1[16];
    {
        f32x4 ra[16], rb[16];
#pragma unroll
        for (int ks = 0; ks < 16; ++ks) {
            ra[ks] = *(const f32x4*)(pA0 + ks * 32);
            rb[ks] = *(const f32x4*)(pA0 + ks * 32 + 4);
        }
#pragma unroll
        for (int ks = 0; ks < 16; ++ks) {
            u32x4 p;
            p.x = cvtpk(ra[ks].x, ra[ks].y); p.y = cvtpk(ra[ks].z, ra[ks].w);
            p.z = cvtpk(rb[ks].x, rb[ks].y); p.w = cvtpk(rb[ks].z, rb[ks].w);
            af0[ks] = *(bf16x8*)&p;
        }
#pragma unroll
        for (int ks = 0; ks < 16; ++ks) {
            ra[ks] = *(const f32x4*)(pA1 + ks * 32);
            rb[ks] = *(const f32x4*)(pA1 + ks * 32 + 4);
        }
#pragma unroll
        for (int ks = 0; ks < 16; ++ks) {
            u32x4 p;
            p.x = cvtpk(ra[ks].x, ra[ks].y); p.y = cvtpk(ra[ks].z, ra[ks].w);
            p.z = cvtpk(rb[ks].x, rb[ks].y); p.w = cvtpk(rb[ks].z, rb[ks].w);
            af1[ks] = *(bf16x8*)&p;
        }
    }

    // ---- Phase 2: K-loop, double-buffered B prefetch ----
    f32x4 acc[2][16] = {};
    bf16x8 bbuf[2][16];
#pragma unroll
    for (int cg = 0; cg < 16; ++cg)
        bbuf[0][cg] = *(const bf16x8*)(pB + (size_t)cg * 512);
#pragma unroll
    for (int ks = 0; ks < 16; ++ks) {
        const int cur = ks & 1;
        const int nxt = cur ^ 1;
        if (ks < 15) {
            const unsigned short* pBn = pB + (size_t)(ks + 1) * 16 * 512;
#pragma unroll
            for (int cg = 0; cg < 16; ++cg)
                bbuf[nxt][cg] = *(const bf16x8*)(pBn + (size_t)cg * 512);
        }
#pragma unroll
        for (int cg = 0; cg < 16; ++cg) {
            acc[0][cg] = __builtin_amdgcn_mfma_f32_16x16x32_bf16(af0[ks], bbuf[cur][cg], acc[0][cg], 0, 0, 0);
            acc[1][cg] = __builtin_amdgcn_mfma_f32_16x16x32_bf16(af1[ks], bbuf[cur][cg], acc[1][cg], 0, 0, 0);
        }
    }

    // ---- epilogue: store hb + fused score dots ----
    float as_[16], ad_[16];
#pragma unroll
    for (int cg = 0; cg < 16; ++cg) {
        int col = cg * 16 + l15;
        as_[cg] = av[col];
        ad_[cg] = av[DOUT + col];
    }
#pragma unroll
    for (int rf = 0; rf < 2; ++rf) {
#pragma unroll
        for (int j = 0; j < 4; ++j) {
            int row = m0 + rf * 16 + g * 4 + j;
            float ps = 0.f, pd = 0.f;
#pragma unroll
            for (int cg = 0; cg < 16; ++cg) {
                float v = acc[rf][cg][j];
                ps += v * as_[cg];
                pd += v * ad_[cg];
            }
#pragma unroll
            for (int off = 1; off < 16; off <<= 1) {
                ps += __shfl_xor(ps, off);
                pd += __shfl_xor(pd, off);
            }
            if (row < M) {
#pragma unroll
                for (int cg = 0; cg < 16; ++cg)
                    hb[(size_t)row * DOUT + cg * 16 + l15] = f2bf(acc[rf][cg][j]);
                if (l15 == 0) {
                    atomicAdd(&s_src[row], ps);
                    atomicAdd(&s_dst[row], pd);
                }
            }
        }
    }
}

// ---------------- degree histogram ----------------
__global__ void hist_k(const int* __restrict__ src, int* __restrict__ deg, int E) {
    int i = blockIdx.x * blockDim.x + threadIdx.x;
    if (i < E) atomicAdd(&deg[src[i]], 1);
}

// ---------------- 3-stage scan: blocksum -> top scan -> block rescan ----------------
__global__ __launch_bounds__(256) void block_sum(const int* __restrict__ deg, int* __restrict__ bsum, int N) {
    __shared__ int wsum[4];
    int b = blockIdx.x, t = threadIdx.x;
    int idx = b * 1024 + t * 4;
    int s = 0;
    if (idx + 3 < N) {
        int4 v = *(const int4*)(deg + idx);
        s = v.x + v.y + v.z + v.w;
    } else {
        for (int i = 0; i < 4; i++) if (idx + i < N) s += deg[idx + i];
    }
#pragma unroll
    for (int off = 32; off > 0; off >>= 1) s += __shfl_xor(s, off);
    if ((t & 63) == 0) wsum[t >> 6] = s;
    __syncthreads();
    if (t == 0) bsum[b] = wsum[0] + wsum[1] + wsum[2] + wsum[3];
}

__global__ void scan_tops(const int* __restrict__ bsum, int* __restrict__ boff,
                          int* __restrict__ rowptr, int nb, int N, int E) {
    int t = threadIdx.x;  // single wave of 64
    int v = (t < nb) ? bsum[t] : 0;
    int x = v;
#pragma unroll
    for (int off = 1; off < 64; off <<= 1) {
        int y = __shfl_up(x, off);
        if (t >= off) x += y;
    }
    if (t < nb) boff[t] = x - v;
    if (t == 0) rowptr[N] = E;
}

__global__ __launch_bounds__(256) void scan_blk(const int* __restrict__ deg, const int* __restrict__ boff,
                                                int* __restrict__ rowptr, int* __restrict__ cursor, int N) {
    __shared__ int wsum[4];
    int b = blockIdx.x, t = threadIdx.x;
    int idx = b * 1024 + t * 4;
    int v0 = 0, v1 = 0, v2 = 0, v3 = 0;
    if (idx + 3 < N) {
        int4 v = *(const int4*)(deg + idx);
        v0 = v.x; v1 = v.y; v2 = v.z; v3 = v.w;
    } else if (idx < N) {
        v0 = deg[idx];
        if (idx + 1 < N) v1 = deg[idx + 1];
        if (idx + 2 < N) v2 = deg[idx + 2];
    }
    int s = v0 + v1 + v2 + v3;
    int lane = t & 63, wid = t >> 6;
    int x = s;
#pragma unroll
    for (int off = 1; off < 64; off <<= 1) {
        int y = __shfl_up(x, off);
        if (lane >= off) x += y;
    }
    if (lane == 63) wsum[wid] = x;
    __syncthreads();
    int add = boff[b];
    for (int ww = 0; ww < wid; ++ww) add += wsum[ww];
    int e0 = add + x - s;
    int e1 = e0 + v0, e2 = e1 + v1, e3 = e2 + v2;
    if (idx < N)     { rowptr[idx] = e0;     cursor[idx] = e0; }
    if (idx + 1 < N) { rowptr[idx + 1] = e1; cursor[idx + 1] = e1; }
    if (idx + 2 < N) { rowptr[idx + 2] = e2; cursor[idx + 2] = e2; }
    if (idx + 3 < N) { rowptr[idx + 3] = e3; cursor[idx + 3] = e3; }
}

// ---------------- edge scoring + CSR scatter (packed pair) ----------------
__global__ void edge_k(const int* __restrict__ src, const int* __restrict__ dst,
                       const float* __restrict__ s_src, const float* __restrict__ s_dst,
                       int* __restrict__ cursor, int2* __restrict__ csr, int E) {
    int i = blockIdx.x * blockDim.x + threadIdx.x;
    if (i >= E) return;
    int s = src[i], d = dst[i];
    float sc = s_src[s] + s_dst[d];
    float lrv = sc > 0.f ? sc : NEG_SLOPE * sc;
    float ev = __expf(-lrv);
    int pos = atomicAdd(&cursor[s], 1);
    csr[pos] = make_int2(d, __float_as_int(ev));
}

// ---------------- per-row gather SpMM (bf16 h) + div + ELU ----------------
__global__ __launch_bounds__(256) void gather_k(const unsigned short* __restrict__ hb,
                                                const int* __restrict__ rowptr,
                                                const int2* __restrict__ csr,
                                                float* __restrict__ out, int N) {
    int gt = blockIdx.x * blockDim.x + threadIdx.x;
    int w = gt >> 6;
    int lane = threadIdx.x & 63;
    if (w >= N) return;
    int s0 = rowptr[w], s1 = rowptr[w + 1];
    float a0 = 0.f, a1 = 0.f, a2 = 0.f, a3 = 0.f, rs = 0.f;
    for (int base = s0; base < s1; base += 64) {
        int cnt = min(64, s1 - base);
        int dv = 0; float ev = 0.f;
        if (lane < cnt) {
            int2 p = csr[base + lane];
            dv = p.x; ev = __int_as_float(p.y);
        }
        int jj = 0;
        for (; jj + 4 <= cnt; jj += 4) {
            int d0 = __shfl(dv, jj), d1 = __shfl(dv, jj + 1), d2 = __shfl(dv, jj + 2), d3 = __shfl(dv, jj + 3);
            float e0 = __shfl(ev, jj), e1 = __shfl(ev, jj + 1), e2 = __shfl(ev, jj + 2), e3 = __shfl(ev, jj + 3);
            ushort4 h0 = *(const ushort4*)(hb + (size_t)d0 * DOUT + lane * 4);
            ushort4 h1 = *(const ushort4*)(hb + (size_t)d1 * DOUT + lane * 4);
            ushort4 h2 = *(const ushort4*)(hb + (size_t)d2 * DOUT + lane * 4);
            ushort4 h3 = *(const ushort4*)(hb + (size_t)d3 * DOUT + lane * 4);
            a0 += e0 * bf2f(h0.x) + e1 * bf2f(h1.x) + e2 * bf2f(h2.x) + e3 * bf2f(h3.x);
            a1 += e0 * bf2f(h0.y) + e1 * bf2f(h1.y) + e2 * bf2f(h2.y) + e3 * bf2f(h3.y);
            a2 += e0 * bf2f(h0.z) + e1 * bf2f(h1.z) + e2 * bf2f(h2.z) + e3 * bf2f(h3.z);
            a3 += e0 * bf2f(h0.w) + e1 * bf2f(h1.w) + e2 * bf2f(h2.w) + e3 * bf2f(h3.w);
            rs += e0 + e1 + e2 + e3;
        }
        for (; jj < cnt; ++jj) {
            int d0 = __shfl(dv, jj);
            float e0 = __shfl(ev, jj);
            ushort4 h0 = *(const ushort4*)(hb + (size_t)d0 * DOUT + lane * 4);
            a0 += e0 * bf2f(h0.x);
            a1 += e0 * bf2f(h0.y);
            a2 += e0 * bf2f(h0.z);
            a3 += e0 * bf2f(h0.w);
            rs += e0;
        }
    }
    float inv = 1.f / rs;
    float4 v;
    v.x = a0 * inv; v.y = a1 * inv; v.z = a2 * inv; v.w = a3 * inv;
    v.x = v.x > 0.f ? v.x : __expf(v.x) - 1.f;
    v.y = v.y > 0.f ? v.y : __expf(v.y) - 1.f;
    v.z = v.z > 0.f ? v.z : __expf(v.z) - 1.f;
    v.w = v.w > 0.f ? v.w : __expf(v.w) - 1.f;
    *(float4*)(out + (size_t)w * DOUT + lane * 4) = v;
}

extern "C" void kernel_launch(void* const* d_in, const int* in_sizes, int n_in,
                              void* d_out, int out_size, void* d_ws, size_t ws_size,
                              hipStream_t stream) {
    const float* x = (const float*)d_in[0];
    const float* W = (const float*)d_in[1];
    const float* a = (const float*)d_in[2];
    const int* edge_src = (const int*)d_in[3];
    const int* edge_dst = (const int*)d_in[4];

    const int N = in_sizes[0] / DIN;
    const int E = in_sizes[3];
    const int nb = (N + 1023) / 1024;

    char* ws = (char*)d_ws;
    size_t off = 0;
    auto alloc = [&](size_t bytes) {
        void* p = ws + off;
        off += (bytes + 15) & ~(size_t)15;
        return p;
    };
    unsigned short* hb = (unsigned short*)alloc((size_t)N * DOUT * 2);
    unsigned short* Bp = (unsigned short*)alloc((size_t)DIN * DOUT * 2);
    int* rowptr = (int*)alloc((size_t)(N + 1) * 4);
    int* deg = (int*)alloc((size_t)N * 4);
    int* cursor = (int*)alloc((size_t)N * 4);
    float* s_src = (float*)alloc((size_t)N * 4);
    float* s_dst = (float*)alloc((size_t)N * 4);
    int2* csr = (int2*)alloc((size_t)E * 8);
    int* bsum = (int*)alloc((size_t)nb * 4);
    int* boff = (int*)alloc((size_t)nb * 4);
    (void)ws_size;

    float* out = (float*)d_out;

    prep<<<(N + 255) / 256, 256, 0, stream>>>(W, Bp, deg, s_src, s_dst, N);
    hist_k<<<(E + 255) / 256, 256, 0, stream>>>(edge_src, deg, E);
    gemm_k<<<(N + 31) / 32, 64, 0, stream>>>(x, Bp, hb, a, s_src, s_dst, N);
    block_sum<<<nb, 256, 0, stream>>>(deg, bsum, N);
    scan_tops<<<1, 64, 0, stream>>>(bsum, boff, rowptr, nb, N, E);
    scan_blk<<<nb, 256, 0, stream>>>(deg, boff, rowptr, cursor, N);
    edge_k<<<(E + 255) / 256, 256, 0, stream>>>(edge_src, edge_dst, s_src, s_dst,
                                                cursor, csr, E);
    gather_k<<<(N + 3) / 4, 256, 0, stream>>>(hb, rowptr, csr, out, N);
}

// Round 11
// 174.910 us; speedup vs baseline: 1.0189x; 1.0189x over previous
//
#include <hip/hip_runtime.h>
#include <math.h>

#define DIN 512
#define DOUT 256
#define NEG_SLOPE 0.01f

typedef __attribute__((ext_vector_type(8))) short bf16x8;
typedef __attribute__((ext_vector_type(4))) float f32x4;
typedef __attribute__((ext_vector_type(4))) unsigned int u32x4;

__device__ __forceinline__ unsigned short f2bf(float f) {
    unsigned int u = __float_as_uint(f);
    unsigned int r = (u + 0x7FFFu + ((u >> 16) & 1u)) >> 16;
    return (unsigned short)r;
}
__device__ __forceinline__ float bf2f(unsigned short u) {
    return __uint_as_float(((unsigned int)u) << 16);
}
__device__ __forceinline__ unsigned int cvtpk(float lo, float hi) {
    unsigned int r;
    asm("v_cvt_pk_bf16_f32 %0, %1, %2" : "=v"(r) : "v"(lo), "v"(hi));
    return r;
}

// ---------------- prep: Bpack = bf16(W) in MFMA fragment order; zero deg/s_src/s_dst --
// Fragment f = ks*16 + cg (ks: K-step of 32, cg: 16-col group). Lane (g,l15) of frag f
// holds W[k = ks*32+g*8 .. +8][col = cg*16+l15]. Stored at Bpack[(f*64+lane)*8].
__global__ void prep(const float* __restrict__ W, unsigned short* __restrict__ Bp,
                     int* __restrict__ deg, float* __restrict__ s_src,
                     float* __restrict__ s_dst, int N) {
    int t = blockIdx.x * blockDim.x + threadIdx.x;
    if (t < (DIN / 32) * (DOUT / 16) * 64) {  // 16384
        int lane = t & 63;
        int cg = (t >> 6) & 15;
        int ks = t >> 10;
        int l15 = lane & 15, g = lane >> 4;
        int col = cg * 16 + l15;
        int k0 = ks * 32 + g * 8;
        ushort4 lo, hi;
        lo.x = f2bf(W[(size_t)(k0 + 0) * DOUT + col]);
        lo.y = f2bf(W[(size_t)(k0 + 1) * DOUT + col]);
        lo.z = f2bf(W[(size_t)(k0 + 2) * DOUT + col]);
        lo.w = f2bf(W[(size_t)(k0 + 3) * DOUT + col]);
        hi.x = f2bf(W[(size_t)(k0 + 4) * DOUT + col]);
        hi.y = f2bf(W[(size_t)(k0 + 5) * DOUT + col]);
        hi.z = f2bf(W[(size_t)(k0 + 6) * DOUT + col]);
        hi.w = f2bf(W[(size_t)(k0 + 7) * DOUT + col]);
        *(ushort4*)(Bp + (size_t)t * 8) = lo;
        *(ushort4*)(Bp + (size_t)t * 8 + 4) = hi;
    }
    if (t < N) { deg[t] = 0; s_src[t] = 0.f; s_dst[t] = 0.f; }
}

// ---------------- GEMM: hb = bf16( x @ W ), fused s_src/s_dst dots ----------
// One wave per block; wave = 32 rows x 128 cols (grid.y picks col half).
// acc[2][8]=64 VGPR; A and B both explicitly double-buffered 1-deep (prefetch ks+1
// before the 16 MFMAs of ks). ~190 VGPR total -> no spill, pipelining headroom.
__global__ __launch_bounds__(64, 2) void gemm_k(const float* __restrict__ x,
                                                const unsigned short* __restrict__ Bp,
                                                unsigned short* __restrict__ hb,
                                                const float* __restrict__ av,
                                                float* __restrict__ s_src,
                                                float* __restrict__ s_dst, int M) {
    const int lane = threadIdx.x;   // one wave per block
    const int l15 = lane & 15;
    const int g = lane >> 4;
    const int m0 = blockIdx.x * 32;
    const int half = blockIdx.y;    // 0..1 : col half (128 cols)

    int r0 = min(m0 + l15, M - 1);
    int r1 = min(m0 + 16 + l15, M - 1);
    const float* pA0 = x + (size_t)r0 * DIN + g * 8;
    const float* pA1 = x + (size_t)r1 * DIN + g * 8;
    // B fragment f = ks*16 + half*8 + cg  at Bp + (f*64+lane)*8
    const unsigned short* pB = Bp + ((size_t)(half * 8) * 64 + lane) * 8;

    f32x4 acc[2][8] = {};
    f32x4 abuf[2][4];
    bf16x8 bbuf[2][8];

    // prologue: load ks=0
#pragma unroll
    for (int i = 0; i < 2; ++i) {
        abuf[0][2 * i] = *(const f32x4*)((i ? pA1 : pA0));
        abuf[0][2 * i + 1] = *(const f32x4*)((i ? pA1 : pA0) + 4);
    }
#pragma unroll
    for (int cg = 0; cg < 8; ++cg)
        bbuf[0][cg] = *(const bf16x8*)(pB + (size_t)cg * 512);

#pragma unroll
    for (int ks = 0; ks < 16; ++ks) {
        const int cur = ks & 1;
        const int nxt = cur ^ 1;
        if (ks < 15) {
            const float* qA0 = pA0 + (ks + 1) * 32;
            const float* qA1 = pA1 + (ks + 1) * 32;
            abuf[nxt][0] = *(const f32x4*)qA0;
            abuf[nxt][1] = *(const f32x4*)(qA0 + 4);
            abuf[nxt][2] = *(const f32x4*)qA1;
            abuf[nxt][3] = *(const f32x4*)(qA1 + 4);
            const unsigned short* pBn = pB + (size_t)(ks + 1) * 16 * 512;
#pragma unroll
            for (int cg = 0; cg < 8; ++cg)
                bbuf[nxt][cg] = *(const bf16x8*)(pBn + (size_t)cg * 512);
        }
        u32x4 p;
        p.x = cvtpk(abuf[cur][0].x, abuf[cur][0].y);
        p.y = cvtpk(abuf[cur][0].z, abuf[cur][0].w);
        p.z = cvtpk(abuf[cur][1].x, abuf[cur][1].y);
        p.w = cvtpk(abuf[cur][1].z, abuf[cur][1].w);
        bf16x8 af0 = *(bf16x8*)&p;
        u32x4 q;
        q.x = cvtpk(abuf[cur][2].x, abuf[cur][2].y);
        q.y = cvtpk(abuf[cur][2].z, abuf[cur][2].w);
        q.z = cvtpk(abuf[cur][3].x, abuf[cur][3].y);
        q.w = cvtpk(abuf[cur][3].z, abuf[cur][3].w);
        bf16x8 af1 = *(bf16x8*)&q;
#pragma unroll
        for (int cg = 0; cg < 8; ++cg) {
            acc[0][cg] = __builtin_amdgcn_mfma_f32_16x16x32_bf16(af0, bbuf[cur][cg], acc[0][cg], 0, 0, 0);
            acc[1][cg] = __builtin_amdgcn_mfma_f32_16x16x32_bf16(af1, bbuf[cur][cg], acc[1][cg], 0, 0, 0);
        }
    }

    // ---- epilogue: store hb + fused score dots ----
    float as_[8], ad_[8];
#pragma unroll
    for (int cg = 0; cg < 8; ++cg) {
        int col = half * 128 + cg * 16 + l15;
        as_[cg] = av[col];
        ad_[cg] = av[DOUT + col];
    }
#pragma unroll
    for (int rf = 0; rf < 2; ++rf) {
#pragma unroll
        for (int j = 0; j < 4; ++j) {
            int row = m0 + rf * 16 + g * 4 + j;
            float ps = 0.f, pd = 0.f;
#pragma unroll
            for (int cg = 0; cg < 8; ++cg) {
                float v = acc[rf][cg][j];
                ps += v * as_[cg];
                pd += v * ad_[cg];
            }
#pragma unroll
            for (int off = 1; off < 16; off <<= 1) {
                ps += __shfl_xor(ps, off);
                pd += __shfl_xor(pd, off);
            }
            if (row < M) {
#pragma unroll
                for (int cg = 0; cg < 8; ++cg)
                    hb[(size_t)row * DOUT + half * 128 + cg * 16 + l15] = f2bf(acc[rf][cg][j]);
                if (l15 == 0) {
                    atomicAdd(&s_src[row], ps);
                    atomicAdd(&s_dst[row], pd);
                }
            }
        }
    }
}

// ---------------- degree histogram ----------------
__global__ void hist_k(const int* __restrict__ src, int* __restrict__ deg, int E) {
    int i = blockIdx.x * blockDim.x + threadIdx.x;
    if (i < E) atomicAdd(&deg[src[i]], 1);
}

// ---------------- 3-stage scan: blocksum -> top scan -> block rescan ----------------
__global__ __launch_bounds__(256) void block_sum(const int* __restrict__ deg, int* __restrict__ bsum, int N) {
    __shared__ int wsum[4];
    int b = blockIdx.x, t = threadIdx.x;
    int idx = b * 1024 + t * 4;
    int s = 0;
    if (idx + 3 < N) {
        int4 v = *(const int4*)(deg + idx);
        s = v.x + v.y + v.z + v.w;
    } else {
        for (int i = 0; i < 4; i++) if (idx + i < N) s += deg[idx + i];
    }
#pragma unroll
    for (int off = 32; off > 0; off >>= 1) s += __shfl_xor(s, off);
    if ((t & 63) == 0) wsum[t >> 6] = s;
    __syncthreads();
    if (t == 0) bsum[b] = wsum[0] + wsum[1] + wsum[2] + wsum[3];
}

__global__ void scan_tops(const int* __restrict__ bsum, int* __restrict__ boff,
                          int* __restrict__ rowptr, int nb, int N, int E) {
    int t = threadIdx.x;  // single wave of 64
    int v = (t < nb) ? bsum[t] : 0;
    int x = v;
#pragma unroll
    for (int off = 1; off < 64; off <<= 1) {
        int y = __shfl_up(x, off);
        if (t >= off) x += y;
    }
    if (t < nb) boff[t] = x - v;
    if (t == 0) rowptr[N] = E;
}

__global__ __launch_bounds__(256) void scan_blk(const int* __restrict__ deg, const int* __restrict__ boff,
                                                int* __restrict__ rowptr, int* __restrict__ cursor, int N) {
    __shared__ int wsum[4];
    int b = blockIdx.x, t = threadIdx.x;
    int idx = b * 1024 + t * 4;
    int v0 = 0, v1 = 0, v2 = 0, v3 = 0;
    if (idx + 3 < N) {
        int4 v = *(const int4*)(deg + idx);
        v0 = v.x; v1 = v.y; v2 = v.z; v3 = v.w;
    } else if (idx < N) {
        v0 = deg[idx];
        if (idx + 1 < N) v1 = deg[idx + 1];
        if (idx + 2 < N) v2 = deg[idx + 2];
    }
    int s = v0 + v1 + v2 + v3;
    int lane = t & 63, wid = t >> 6;
    int x = s;
#pragma unroll
    for (int off = 1; off < 64; off <<= 1) {
        int y = __shfl_up(x, off);
        if (lane >= off) x += y;
    }
    if (lane == 63) wsum[wid] = x;
    __syncthreads();
    int add = boff[b];
    for (int ww = 0; ww < wid; ++ww) add += wsum[ww];
    int e0 = add + x - s;
    int e1 = e0 + v0, e2 = e1 + v1, e3 = e2 + v2;
    if (idx < N)     { rowptr[idx] = e0;     cursor[idx] = e0; }
    if (idx + 1 < N) { rowptr[idx + 1] = e1; cursor[idx + 1] = e1; }
    if (idx + 2 < N) { rowptr[idx + 2] = e2; cursor[idx + 2] = e2; }
    if (idx + 3 < N) { rowptr[idx + 3] = e3; cursor[idx + 3] = e3; }
}

// ---------------- edge scoring + CSR scatter (packed pair) ----------------
__global__ void edge_k(const int* __restrict__ src, const int* __restrict__ dst,
                       const float* __restrict__ s_src, const float* __restrict__ s_dst,
                       int* __restrict__ cursor, int2* __restrict__ csr, int E) {
    int i = blockIdx.x * blockDim.x + threadIdx.x;
    if (i >= E) return;
    int s = src[i], d = dst[i];
    float sc = s_src[s] + s_dst[d];
    float lrv = sc > 0.f ? sc : NEG_SLOPE * sc;
    float ev = __expf(-lrv);
    int pos = atomicAdd(&cursor[s], 1);
    csr[pos] = make_int2(d, __float_as_int(ev));
}

// ---------------- per-row gather SpMM (bf16 h) + div + ELU ----------------
__global__ __launch_bounds__(256) void gather_k(const unsigned short* __restrict__ hb,
                                                const int* __restrict__ rowptr,
                                                const int2* __restrict__ csr,
                                                float* __restrict__ out, int N) {
    int gt = blockIdx.x * blockDim.x + threadIdx.x;
    int w = gt >> 6;
    int lane = threadIdx.x & 63;
    if (w >= N) return;
    int s0 = rowptr[w], s1 = rowptr[w + 1];
    float a0 = 0.f, a1 = 0.f, a2 = 0.f, a3 = 0.f, rs = 0.f;
    for (int base = s0; base < s1; base += 64) {
        int cnt = min(64, s1 - base);
        int dv = 0; float ev = 0.f;
        if (lane < cnt) {
            int2 p = csr[base + lane];
            dv = p.x; ev = __int_as_float(p.y);
        }
        int jj = 0;
        for (; jj + 4 <= cnt; jj += 4) {
            int d0 = __shfl(dv, jj), d1 = __shfl(dv, jj + 1), d2 = __shfl(dv, jj + 2), d3 = __shfl(dv, jj + 3);
            float e0 = __shfl(ev, jj), e1 = __shfl(ev, jj + 1), e2 = __shfl(ev, jj + 2), e3 = __shfl(ev, jj + 3);
            ushort4 h0 = *(const ushort4*)(hb + (size_t)d0 * DOUT + lane * 4);
            ushort4 h1 = *(const ushort4*)(hb + (size_t)d1 * DOUT + lane * 4);
            ushort4 h2 = *(const ushort4*)(hb + (size_t)d2 * DOUT + lane * 4);
            ushort4 h3 = *(const ushort4*)(hb + (size_t)d3 * DOUT + lane * 4);
            a0 += e0 * bf2f(h0.x) + e1 * bf2f(h1.x) + e2 * bf2f(h2.x) + e3 * bf2f(h3.x);
            a1 += e0 * bf2f(h0.y) + e1 * bf2f(h1.y) + e2 * bf2f(h2.y) + e3 * bf2f(h3.y);
            a2 += e0 * bf2f(h0.z) + e1 * bf2f(h1.z) + e2 * bf2f(h2.z) + e3 * bf2f(h3.z);
            a3 += e0 * bf2f(h0.w) + e1 * bf2f(h1.w) + e2 * bf2f(h2.w) + e3 * bf2f(h3.w);
            rs += e0 + e1 + e2 + e3;
        }
        for (; jj < cnt; ++jj) {
            int d0 = __shfl(dv, jj);
            float e0 = __shfl(ev, jj);
            ushort4 h0 = *(const ushort4*)(hb + (size_t)d0 * DOUT + lane * 4);
            a0 += e0 * bf2f(h0.x);
            a1 += e0 * bf2f(h0.y);
            a2 += e0 * bf2f(h0.z);
            a3 += e0 * bf2f(h0.w);
            rs += e0;
        }
    }
    float inv = 1.f / rs;
    float4 v;
    v.x = a0 * inv; v.y = a1 * inv; v.z = a2 * inv; v.w = a3 * inv;
    v.x = v.x > 0.f ? v.x : __expf(v.x) - 1.f;
    v.y = v.y > 0.f ? v.y : __expf(v.y) - 1.f;
    v.z = v.z > 0.f ? v.z : __expf(v.z) - 1.f;
    v.w = v.w > 0.f ? v.w : __expf(v.w) - 1.f;
    *(float4*)(out + (size_t)w * DOUT + lane * 4) = v;
}

extern "C" void kernel_launch(void* const* d_in, const int* in_sizes, int n_in,
                              void* d_out, int out_size, void* d_ws, size_t ws_size,
                              hipStream_t stream) {
    const float* x = (const float*)d_in[0];
    const float* W = (const float*)d_in[1];
    const float* a = (const float*)d_in[2];
    const int* edge_src = (const int*)d_in[3];
    const int* edge_dst = (const int*)d_in[4];

    const int N = in_sizes[0] / DIN;
    const int E = in_sizes[3];
    const int nb = (N + 1023) / 1024;

    char* ws = (char*)d_ws;
    size_t off = 0;
    auto alloc = [&](size_t bytes) {
        void* p = ws + off;
        off += (bytes + 15) & ~(size_t)15;
        return p;
    };
    unsigned short* hb = (unsigned short*)alloc((size_t)N * DOUT * 2);
    unsigned short* Bp = (unsigned short*)alloc((size_t)DIN * DOUT * 2);
    int* rowptr = (int*)alloc((size_t)(N + 1) * 4);
    int* deg = (int*)alloc((size_t)N * 4);
    int* cursor = (int*)alloc((size_t)N * 4);
    float* s_src = (float*)alloc((size_t)N * 4);
    float* s_dst = (float*)alloc((size_t)N * 4);
    int2* csr = (int2*)alloc((size_t)E * 8);
    int* bsum = (int*)alloc((size_t)nb * 4);
    int* boff = (int*)alloc((size_t)nb * 4);
    (void)ws_size;

    float* out = (float*)d_out;

    prep<<<(N + 255) / 256, 256, 0, stream>>>(W, Bp, deg, s_src, s_dst, N);
    hist_k<<<(E + 255) / 256, 256, 0, stream>>>(edge_src, deg, E);
    dim3 ggrid((N + 31) / 32, 2);
    gemm_k<<<ggrid, 64, 0, stream>>>(x, Bp, hb, a, s_src, s_dst, N);
    block_sum<<<nb, 256, 0, stream>>>(deg, bsum, N);
    scan_tops<<<1, 64, 0, stream>>>(bsum, boff, rowptr, nb, N, E);
    scan_blk<<<nb, 256, 0, stream>>>(deg, boff, rowptr, cursor, N);
    edge_k<<<(E + 255) / 256, 256, 0, stream>>>(edge_src, edge_dst, s_src, s_dst,
                                                cursor, csr, E);
    gather_k<<<(N + 3) / 4, 256, 0, stream>>>(hb, rowptr, csr, out, N);
}

// Round 12
// 147.347 us; speedup vs baseline: 1.2095x; 1.1871x over previous
//
#include <hip/hip_runtime.h>
#include <math.h>

#define DIN 512
#define DOUT 256
#define NEG_SLOPE 0.01f

typedef __attribute__((ext_vector_type(8))) short bf16x8;
typedef __attribute__((ext_vector_type(4))) float f32x4;
typedef __attribute__((ext_vector_type(4))) unsigned int u32x4;

__device__ __forceinline__ unsigned short f2bf(float f) {
    unsigned int u = __float_as_uint(f);
    unsigned int r = (u + 0x7FFFu + ((u >> 16) & 1u)) >> 16;
    return (unsigned short)r;
}
__device__ __forceinline__ float bf2f(unsigned short u) {
    return __uint_as_float(((unsigned int)u) << 16);
}
__device__ __forceinline__ unsigned int cvtpk(float lo, float hi) {
    unsigned int r;
    asm("v_cvt_pk_bf16_f32 %0, %1, %2" : "=v"(r) : "v"(lo), "v"(hi));
    return r;
}
__device__ __forceinline__ void gload16(const void* g, void* l) {
    __builtin_amdgcn_global_load_lds(
        (const __attribute__((address_space(1))) void*)g,
        (__attribute__((address_space(3))) void*)l, 16, 0, 0);
}

// ---------------- prep: Bpack = bf16(W) in MFMA fragment order; zero deg/s_src/s_dst --
// Fragment f = ks*16 + cg. Lane (g,l15) of frag f holds W[ks*32+g*8 .. +8][cg*16+l15].
__global__ void prep(const float* __restrict__ W, unsigned short* __restrict__ Bp,
                     int* __restrict__ deg, float* __restrict__ s_src,
                     float* __restrict__ s_dst, int N) {
    int t = blockIdx.x * blockDim.x + threadIdx.x;
    if (t < (DIN / 32) * (DOUT / 16) * 64) {  // 16384
        int lane = t & 63;
        int cg = (t >> 6) & 15;
        int ks = t >> 10;
        int l15 = lane & 15, g = lane >> 4;
        int col = cg * 16 + l15;
        int k0 = ks * 32 + g * 8;
        ushort4 lo, hi;
        lo.x = f2bf(W[(size_t)(k0 + 0) * DOUT + col]);
        lo.y = f2bf(W[(size_t)(k0 + 1) * DOUT + col]);
        lo.z = f2bf(W[(size_t)(k0 + 2) * DOUT + col]);
        lo.w = f2bf(W[(size_t)(k0 + 3) * DOUT + col]);
        hi.x = f2bf(W[(size_t)(k0 + 4) * DOUT + col]);
        hi.y = f2bf(W[(size_t)(k0 + 5) * DOUT + col]);
        hi.z = f2bf(W[(size_t)(k0 + 6) * DOUT + col]);
        hi.w = f2bf(W[(size_t)(k0 + 7) * DOUT + col]);
        *(ushort4*)(Bp + (size_t)t * 8) = lo;
        *(ushort4*)(Bp + (size_t)t * 8 + 4) = hi;
    }
    if (t < N) { deg[t] = 0; s_src[t] = 0.f; s_dst[t] = 0.f; }
}

// ---------------- GEMM: hb = bf16( x @ W ), fused s_src/s_dst dots ----------
// 1 wave/block, wave = 32 rows x 128 cols (grid.y = col half). A staged WAVE-PRIVATE
// into LDS via global_load_lds (fire-and-forget, no VGPR held), 1-deep pipeline with
// counted s_waitcnt vmcnt(4). XOR-swizzled A slots (pre-swizzled global source).
// B frags direct from L2-hot Bp. No barriers anywhere.
__global__ __launch_bounds__(64, 3) void gemm_k(const float* __restrict__ x,
                                                const unsigned short* __restrict__ Bp,
                                                unsigned short* __restrict__ hb,
                                                const float* __restrict__ av,
                                                float* __restrict__ s_src,
                                                float* __restrict__ s_dst, int M) {
    __shared__ unsigned char As[8192];   // 2 bufs x 4KB (32 rows x 8 swizzled 16B slots)
    const int lane = threadIdx.x;
    const int l15 = lane & 15;
    const int g = lane >> 4;
    const int m0 = blockIdx.x * 32;
    const int half = blockIdx.y;

    // stage A k-chunk ks into buffer bb: linear dest, swizzled per-lane source
    auto stage = [&](int bb, int ks) {
#pragma unroll
        for (int it = 0; it < 4; ++it) {
            int s = it * 64 + lane;
            int row = s >> 3;
            int slot = s & 7;
            int q = slot ^ (row & 7);
            int rg = min(m0 + row, M - 1);
            const float* src = x + (size_t)rg * DIN + ks * 32 + q * 4;
            gload16(src, As + bb * 4096 + it * 1024);
        }
    };

    const unsigned short* pB = Bp + ((size_t)(half * 8) * 64 + lane) * 8;
    f32x4 acc[2][8] = {};

    stage(0, 0);
#pragma unroll
    for (int ks = 0; ks < 16; ++ks) {
        const int bb = ks & 1;
        if (ks < 15) {
            stage(bb ^ 1, ks + 1);
            asm volatile("s_waitcnt vmcnt(4)" ::: "memory");
        } else {
            asm volatile("s_waitcnt vmcnt(0)" ::: "memory");
        }
        const unsigned char* Ab = As + bb * 4096;
        const int rr0 = l15, rr1 = l15 + 16;
        f32x4 v0 = *(const f32x4*)(Ab + rr0 * 128 + (((2 * g) ^ (rr0 & 7)) << 4));
        f32x4 v1 = *(const f32x4*)(Ab + rr0 * 128 + (((2 * g + 1) ^ (rr0 & 7)) << 4));
        f32x4 w0 = *(const f32x4*)(Ab + rr1 * 128 + (((2 * g) ^ (rr1 & 7)) << 4));
        f32x4 w1 = *(const f32x4*)(Ab + rr1 * 128 + (((2 * g + 1) ^ (rr1 & 7)) << 4));
        u32x4 p;
        p.x = cvtpk(v0.x, v0.y); p.y = cvtpk(v0.z, v0.w);
        p.z = cvtpk(v1.x, v1.y); p.w = cvtpk(v1.z, v1.w);
        bf16x8 af0 = *(bf16x8*)&p;
        u32x4 q;
        q.x = cvtpk(w0.x, w0.y); q.y = cvtpk(w0.z, w0.w);
        q.z = cvtpk(w1.x, w1.y); q.w = cvtpk(w1.z, w1.w);
        bf16x8 af1 = *(bf16x8*)&q;
        const unsigned short* pBks = pB + (size_t)ks * 16 * 512;
#pragma unroll
        for (int cg = 0; cg < 8; ++cg) {
            bf16x8 bfr = *(const bf16x8*)(pBks + (size_t)cg * 512);
            acc[0][cg] = __builtin_amdgcn_mfma_f32_16x16x32_bf16(af0, bfr, acc[0][cg], 0, 0, 0);
            acc[1][cg] = __builtin_amdgcn_mfma_f32_16x16x32_bf16(af1, bfr, acc[1][cg], 0, 0, 0);
        }
    }

    // ---- epilogue: store hb + fused score dots ----
    float as_[8], ad_[8];
#pragma unroll
    for (int cg = 0; cg < 8; ++cg) {
        int col = half * 128 + cg * 16 + l15;
        as_[cg] = av[col];
        ad_[cg] = av[DOUT + col];
    }
#pragma unroll
    for (int rf = 0; rf < 2; ++rf) {
#pragma unroll
        for (int j = 0; j < 4; ++j) {
            int row = m0 + rf * 16 + g * 4 + j;
            float ps = 0.f, pd = 0.f;
#pragma unroll
            for (int cg = 0; cg < 8; ++cg) {
                float v = acc[rf][cg][j];
                ps += v * as_[cg];
                pd += v * ad_[cg];
            }
#pragma unroll
            for (int off = 1; off < 16; off <<= 1) {
                ps += __shfl_xor(ps, off);
                pd += __shfl_xor(pd, off);
            }
            if (row < M) {
#pragma unroll
                for (int cg = 0; cg < 8; ++cg)
                    hb[(size_t)row * DOUT + half * 128 + cg * 16 + l15] = f2bf(acc[rf][cg][j]);
                if (l15 == 0) {
                    atomicAdd(&s_src[row], ps);
                    atomicAdd(&s_dst[row], pd);
                }
            }
        }
    }
}

// ---------------- degree histogram ----------------
__global__ void hist_k(const int* __restrict__ src, int* __restrict__ deg, int E) {
    int i = blockIdx.x * blockDim.x + threadIdx.x;
    if (i < E) atomicAdd(&deg[src[i]], 1);
}

// ---------------- 3-stage scan: blocksum -> top scan -> block rescan ----------------
__global__ __launch_bounds__(256) void block_sum(const int* __restrict__ deg, int* __restrict__ bsum, int N) {
    __shared__ int wsum[4];
    int b = blockIdx.x, t = threadIdx.x;
    int idx = b * 1024 + t * 4;
    int s = 0;
    if (idx + 3 < N) {
        int4 v = *(const int4*)(deg + idx);
        s = v.x + v.y + v.z + v.w;
    } else {
        for (int i = 0; i < 4; i++) if (idx + i < N) s += deg[idx + i];
    }
#pragma unroll
    for (int off = 32; off > 0; off >>= 1) s += __shfl_xor(s, off);
    if ((t & 63) == 0) wsum[t >> 6] = s;
    __syncthreads();
    if (t == 0) bsum[b] = wsum[0] + wsum[1] + wsum[2] + wsum[3];
}

__global__ void scan_tops(const int* __restrict__ bsum, int* __restrict__ boff,
                          int* __restrict__ rowptr, int nb, int N, int E) {
    int t = threadIdx.x;  // single wave of 64
    int v = (t < nb) ? bsum[t] : 0;
    int x = v;
#pragma unroll
    for (int off = 1; off < 64; off <<= 1) {
        int y = __shfl_up(x, off);
        if (t >= off) x += y;
    }
    if (t < nb) boff[t] = x - v;
    if (t == 0) rowptr[N] = E;
}

__global__ __launch_bounds__(256) void scan_blk(const int* __restrict__ deg, const int* __restrict__ boff,
                                                int* __restrict__ rowptr, int* __restrict__ cursor, int N) {
    __shared__ int wsum[4];
    int b = blockIdx.x, t = threadIdx.x;
    int idx = b * 1024 + t * 4;
    int v0 = 0, v1 = 0, v2 = 0, v3 = 0;
    if (idx + 3 < N) {
        int4 v = *(const int4*)(deg + idx);
        v0 = v.x; v1 = v.y; v2 = v.z; v3 = v.w;
    } else if (idx < N) {
        v0 = deg[idx];
        if (idx + 1 < N) v1 = deg[idx + 1];
        if (idx + 2 < N) v2 = deg[idx + 2];
    }
    int s = v0 + v1 + v2 + v3;
    int lane = t & 63, wid = t >> 6;
    int x = s;
#pragma unroll
    for (int off = 1; off < 64; off <<= 1) {
        int y = __shfl_up(x, off);
        if (lane >= off) x += y;
    }
    if (lane == 63) wsum[wid] = x;
    __syncthreads();
    int add = boff[b];
    for (int ww = 0; ww < wid; ++ww) add += wsum[ww];
    int e0 = add + x - s;
    int e1 = e0 + v0, e2 = e1 + v1, e3 = e2 + v2;
    if (idx < N)     { rowptr[idx] = e0;     cursor[idx] = e0; }
    if (idx + 1 < N) { rowptr[idx + 1] = e1; cursor[idx + 1] = e1; }
    if (idx + 2 < N) { rowptr[idx + 2] = e2; cursor[idx + 2] = e2; }
    if (idx + 3 < N) { rowptr[idx + 3] = e3; cursor[idx + 3] = e3; }
}

// ---------------- edge scoring + CSR scatter (packed pair) ----------------
__global__ void edge_k(const int* __restrict__ src, const int* __restrict__ dst,
                       const float* __restrict__ s_src, const float* __restrict__ s_dst,
                       int* __restrict__ cursor, int2* __restrict__ csr, int E) {
    int i = blockIdx.x * blockDim.x + threadIdx.x;
    if (i >= E) return;
    int s = src[i], d = dst[i];
    float sc = s_src[s] + s_dst[d];
    float lrv = sc > 0.f ? sc : NEG_SLOPE * sc;
    float ev = __expf(-lrv);
    int pos = atomicAdd(&cursor[s], 1);
    csr[pos] = make_int2(d, __float_as_int(ev));
}

// ---------------- per-row gather SpMM (bf16 h) + div + ELU ----------------
__global__ __launch_bounds__(256) void gather_k(const unsigned short* __restrict__ hb,
                                                const int* __restrict__ rowptr,
                                                const int2* __restrict__ csr,
                                                float* __restrict__ out, int N) {
    int gt = blockIdx.x * blockDim.x + threadIdx.x;
    int w = gt >> 6;
    int lane = threadIdx.x & 63;
    if (w >= N) return;
    int s0 = rowptr[w], s1 = rowptr[w + 1];
    float a0 = 0.f, a1 = 0.f, a2 = 0.f, a3 = 0.f, rs = 0.f;
    for (int base = s0; base < s1; base += 64) {
        int cnt = min(64, s1 - base);
        int dv = 0; float ev = 0.f;
        if (lane < cnt) {
            int2 p = csr[base + lane];
            dv = p.x; ev = __int_as_float(p.y);
        }
        int jj = 0;
        for (; jj + 4 <= cnt; jj += 4) {
            int d0 = __shfl(dv, jj), d1 = __shfl(dv, jj + 1), d2 = __shfl(dv, jj + 2), d3 = __shfl(dv, jj + 3);
            float e0 = __shfl(ev, jj), e1 = __shfl(ev, jj + 1), e2 = __shfl(ev, jj + 2), e3 = __shfl(ev, jj + 3);
            ushort4 h0 = *(const ushort4*)(hb + (size_t)d0 * DOUT + lane * 4);
            ushort4 h1 = *(const ushort4*)(hb + (size_t)d1 * DOUT + lane * 4);
            ushort4 h2 = *(const ushort4*)(hb + (size_t)d2 * DOUT + lane * 4);
            ushort4 h3 = *(const ushort4*)(hb + (size_t)d3 * DOUT + lane * 4);
            a0 += e0 * bf2f(h0.x) + e1 * bf2f(h1.x) + e2 * bf2f(h2.x) + e3 * bf2f(h3.x);
            a1 += e0 * bf2f(h0.y) + e1 * bf2f(h1.y) + e2 * bf2f(h2.y) + e3 * bf2f(h3.y);
            a2 += e0 * bf2f(h0.z) + e1 * bf2f(h1.z) + e2 * bf2f(h2.z) + e3 * bf2f(h3.z);
            a3 += e0 * bf2f(h0.w) + e1 * bf2f(h1.w) + e2 * bf2f(h2.w) + e3 * bf2f(h3.w);
            rs += e0 + e1 + e2 + e3;
        }
        for (; jj < cnt; ++jj) {
            int d0 = __shfl(dv, jj);
            float e0 = __shfl(ev, jj);
            ushort4 h0 = *(const ushort4*)(hb + (size_t)d0 * DOUT + lane * 4);
            a0 += e0 * bf2f(h0.x);
            a1 += e0 * bf2f(h0.y);
            a2 += e0 * bf2f(h0.z);
            a3 += e0 * bf2f(h0.w);
            rs += e0;
        }
    }
    float inv = 1.f / rs;
    float4 v;
    v.x = a0 * inv; v.y = a1 * inv; v.z = a2 * inv; v.w = a3 * inv;
    v.x = v.x > 0.f ? v.x : __expf(v.x) - 1.f;
    v.y = v.y > 0.f ? v.y : __expf(v.y) - 1.f;
    v.z = v.z > 0.f ? v.z : __expf(v.z) - 1.f;
    v.w = v.w > 0.f ? v.w : __expf(v.w) - 1.f;
    *(float4*)(out + (size_t)w * DOUT + lane * 4) = v;
}

extern "C" void kernel_launch(void* const* d_in, const int* in_sizes, int n_in,
                              void* d_out, int out_size, void* d_ws, size_t ws_size,
                              hipStream_t stream) {
    const float* x = (const float*)d_in[0];
    const float* W = (const float*)d_in[1];
    const float* a = (const float*)d_in[2];
    const int* edge_src = (const int*)d_in[3];
    const int* edge_dst = (const int*)d_in[4];

    const int N = in_sizes[0] / DIN;
    const int E = in_sizes[3];
    const int nb = (N + 1023) / 1024;

    char* ws = (char*)d_ws;
    size_t off = 0;
    auto alloc = [&](size_t bytes) {
        void* p = ws + off;
        off += (bytes + 15) & ~(size_t)15;
        return p;
    };
    unsigned short* hb = (unsigned short*)alloc((size_t)N * DOUT * 2);
    unsigned short* Bp = (unsigned short*)alloc((size_t)DIN * DOUT * 2);
    int* rowptr = (int*)alloc((size_t)(N + 1) * 4);
    int* deg = (int*)alloc((size_t)N * 4);
    int* cursor = (int*)alloc((size_t)N * 4);
    float* s_src = (float*)alloc((size_t)N * 4);
    float* s_dst = (float*)alloc((size_t)N * 4);
    int2* csr = (int2*)alloc((size_t)E * 8);
    int* bsum = (int*)alloc((size_t)nb * 4);
    int* boff = (int*)alloc((size_t)nb * 4);
    (void)ws_size;

    float* out = (float*)d_out;

    prep<<<(N + 255) / 256, 256, 0, stream>>>(W, Bp, deg, s_src, s_dst, N);
    hist_k<<<(E + 255) / 256, 256, 0, stream>>>(edge_src, deg, E);
    dim3 ggrid((N + 31) / 32, 2);
    gemm_k<<<ggrid, 64, 0, stream>>>(x, Bp, hb, a, s_src, s_dst, N);
    block_sum<<<nb, 256, 0, stream>>>(deg, bsum, N);
    scan_tops<<<1, 64, 0, stream>>>(bsum, boff, rowptr, nb, N, E);
    scan_blk<<<nb, 256, 0, stream>>>(deg, boff, rowptr, cursor, N);
    edge_k<<<(E + 255) / 256, 256, 0, stream>>>(edge_src, edge_dst, s_src, s_dst,
                                                cursor, csr, E);
    gather_k<<<(N + 3) / 4, 256, 0, stream>>>(hb, rowptr, csr, out, N);
}

// Round 13
// 143.517 us; speedup vs baseline: 1.2418x; 1.0267x over previous
//
#include <hip/hip_runtime.h>
#include <math.h>

#define DIN 512
#define DOUT 256
#define NEG_SLOPE 0.01f

typedef __attribute__((ext_vector_type(8))) short bf16x8;
typedef __attribute__((ext_vector_type(4))) float f32x4;
typedef __attribute__((ext_vector_type(4))) unsigned int u32x4;

__device__ __forceinline__ unsigned short f2bf(float f) {
    unsigned int u = __float_as_uint(f);
    unsigned int r = (u + 0x7FFFu + ((u >> 16) & 1u)) >> 16;
    return (unsigned short)r;
}
__device__ __forceinline__ float bf2f(unsigned short u) {
    return __uint_as_float(((unsigned int)u) << 16);
}
__device__ __forceinline__ unsigned int cvtpk(float lo, float hi) {
    unsigned int r;
    asm("v_cvt_pk_bf16_f32 %0, %1, %2" : "=v"(r) : "v"(lo), "v"(hi));
    return r;
}
__device__ __forceinline__ void gload16(const void* g, void* l) {
    __builtin_amdgcn_global_load_lds(
        (const __attribute__((address_space(1))) void*)g,
        (__attribute__((address_space(3))) void*)l, 16, 0, 0);
}

// ---------------- prep: Bpack = bf16(W) in MFMA fragment order; zero deg/s_src/s_dst --
// Fragment f = ks*16 + cg. Lane (g,l15) of frag f holds W[ks*32+g*8 .. +8][cg*16+l15].
__global__ void prep(const float* __restrict__ W, unsigned short* __restrict__ Bp,
                     int* __restrict__ deg, float* __restrict__ s_src,
                     float* __restrict__ s_dst, int N) {
    int t = blockIdx.x * blockDim.x + threadIdx.x;
    if (t < (DIN / 32) * (DOUT / 16) * 64) {  // 16384
        int lane = t & 63;
        int cg = (t >> 6) & 15;
        int ks = t >> 10;
        int l15 = lane & 15, g = lane >> 4;
        int col = cg * 16 + l15;
        int k0 = ks * 32 + g * 8;
        ushort4 lo, hi;
        lo.x = f2bf(W[(size_t)(k0 + 0) * DOUT + col]);
        lo.y = f2bf(W[(size_t)(k0 + 1) * DOUT + col]);
        lo.z = f2bf(W[(size_t)(k0 + 2) * DOUT + col]);
        lo.w = f2bf(W[(size_t)(k0 + 3) * DOUT + col]);
        hi.x = f2bf(W[(size_t)(k0 + 4) * DOUT + col]);
        hi.y = f2bf(W[(size_t)(k0 + 5) * DOUT + col]);
        hi.z = f2bf(W[(size_t)(k0 + 6) * DOUT + col]);
        hi.w = f2bf(W[(size_t)(k0 + 7) * DOUT + col]);
        *(ushort4*)(Bp + (size_t)t * 8) = lo;
        *(ushort4*)(Bp + (size_t)t * 8 + 4) = hi;
    }
    if (t < N) { deg[t] = 0; s_src[t] = 0.f; s_dst[t] = 0.f; }
}

// ---------------- GEMM: hb = bf16( x @ W ), fused s_src/s_dst dots ----------
// 1 wave/block, 32 rows x 128 cols. A staged wave-private via global_load_lds into
// 4 LDS buffers, 2-deep pipeline; B(ks+1) prefetched into regs before the fence.
// Counted s_waitcnt (NO memory clobber) + sched_barrier(0) brackets. No barriers.
__global__ __launch_bounds__(64, 3) void gemm_k(const float* __restrict__ x,
                                                const unsigned short* __restrict__ Bp,
                                                unsigned short* __restrict__ hb,
                                                const float* __restrict__ av,
                                                float* __restrict__ s_src,
                                                float* __restrict__ s_dst, int M) {
    __shared__ unsigned char As[16384];  // 4 bufs x 4KB (32 rows x 8 swizzled 16B slots)
    const int lane = threadIdx.x;
    const int l15 = lane & 15;
    const int g = lane >> 4;
    const int m0 = blockIdx.x * 32;
    const int half = blockIdx.y;

    auto stage = [&](int bb, int ks) {
#pragma unroll
        for (int it = 0; it < 4; ++it) {
            int s = it * 64 + lane;
            int row = s >> 3;
            int slot = s & 7;
            int q = slot ^ (row & 7);
            int rg = min(m0 + row, M - 1);
            const float* src = x + (size_t)rg * DIN + ks * 32 + q * 4;
            gload16(src, As + bb * 4096 + it * 1024);
        }
    };

    const unsigned short* pB = Bp + ((size_t)(half * 8) * 64 + lane) * 8;
    f32x4 acc[2][8] = {};
    bf16x8 bB[2][8];

    // prologue: 2 stages ahead + B(0)
    stage(0, 0);
    stage(1, 1);
#pragma unroll
    for (int cg = 0; cg < 8; ++cg)
        bB[0][cg] = *(const bf16x8*)(pB + (size_t)cg * 512);

#pragma unroll
    for (int ks = 0; ks < 16; ++ks) {
        if (ks < 14) stage((ks + 2) & 3, ks + 2);
        if (ks < 15) {
            const unsigned short* pBn = pB + (size_t)(ks + 1) * 16 * 512;
#pragma unroll
            for (int cg = 0; cg < 8; ++cg)
                bB[(ks + 1) & 1][cg] = *(const bf16x8*)(pBn + (size_t)cg * 512);
        }
        __builtin_amdgcn_sched_barrier(0);
        if (ks < 14)      asm volatile("s_waitcnt vmcnt(24)");
        else if (ks == 14) asm volatile("s_waitcnt vmcnt(20)");
        else               asm volatile("s_waitcnt vmcnt(16)");
        __builtin_amdgcn_sched_barrier(0);
        const unsigned char* Ab = As + (ks & 3) * 4096;
        const int rr0 = l15, rr1 = l15 + 16;
        f32x4 v0 = *(const f32x4*)(Ab + rr0 * 128 + (((2 * g) ^ (rr0 & 7)) << 4));
        f32x4 v1 = *(const f32x4*)(Ab + rr0 * 128 + (((2 * g + 1) ^ (rr0 & 7)) << 4));
        f32x4 w0 = *(const f32x4*)(Ab + rr1 * 128 + (((2 * g) ^ (rr1 & 7)) << 4));
        f32x4 w1 = *(const f32x4*)(Ab + rr1 * 128 + (((2 * g + 1) ^ (rr1 & 7)) << 4));
        u32x4 p;
        p.x = cvtpk(v0.x, v0.y); p.y = cvtpk(v0.z, v0.w);
        p.z = cvtpk(v1.x, v1.y); p.w = cvtpk(v1.z, v1.w);
        bf16x8 af0 = *(bf16x8*)&p;
        u32x4 q;
        q.x = cvtpk(w0.x, w0.y); q.y = cvtpk(w0.z, w0.w);
        q.z = cvtpk(w1.x, w1.y); q.w = cvtpk(w1.z, w1.w);
        bf16x8 af1 = *(bf16x8*)&q;
#pragma unroll
        for (int cg = 0; cg < 8; ++cg) {
            acc[0][cg] = __builtin_amdgcn_mfma_f32_16x16x32_bf16(af0, bB[ks & 1][cg], acc[0][cg], 0, 0, 0);
            acc[1][cg] = __builtin_amdgcn_mfma_f32_16x16x32_bf16(af1, bB[ks & 1][cg], acc[1][cg], 0, 0, 0);
        }
    }

    // ---- epilogue: store hb + fused score dots ----
    float as_[8], ad_[8];
#pragma unroll
    for (int cg = 0; cg < 8; ++cg) {
        int col = half * 128 + cg * 16 + l15;
        as_[cg] = av[col];
        ad_[cg] = av[DOUT + col];
    }
#pragma unroll
    for (int rf = 0; rf < 2; ++rf) {
#pragma unroll
        for (int j = 0; j < 4; ++j) {
            int row = m0 + rf * 16 + g * 4 + j;
            float ps = 0.f, pd = 0.f;
#pragma unroll
            for (int cg = 0; cg < 8; ++cg) {
                float v = acc[rf][cg][j];
                ps += v * as_[cg];
                pd += v * ad_[cg];
            }
#pragma unroll
            for (int off = 1; off < 16; off <<= 1) {
                ps += __shfl_xor(ps, off);
                pd += __shfl_xor(pd, off);
            }
            if (row < M) {
#pragma unroll
                for (int cg = 0; cg < 8; ++cg)
                    hb[(size_t)row * DOUT + half * 128 + cg * 16 + l15] = f2bf(acc[rf][cg][j]);
                if (l15 == 0) {
                    atomicAdd(&s_src[row], ps);
                    atomicAdd(&s_dst[row], pd);
                }
            }
        }
    }
}

// ---------------- degree histogram (int4 vectorized) ----------------
__global__ void hist_k(const int* __restrict__ src, int* __restrict__ deg, int E) {
    int i = (blockIdx.x * blockDim.x + threadIdx.x) * 4;
    if (i + 3 < E) {
        int4 v = *(const int4*)(src + i);
        atomicAdd(&deg[v.x], 1);
        atomicAdd(&deg[v.y], 1);
        atomicAdd(&deg[v.z], 1);
        atomicAdd(&deg[v.w], 1);
    } else {
        for (int j = i; j < E; ++j) atomicAdd(&deg[src[j]], 1);
    }
}

// ---------------- 2-stage scan: blocksum -> block rescan (tops folded in) ----------
__global__ __launch_bounds__(256) void block_sum(const int* __restrict__ deg, int* __restrict__ bsum, int N) {
    __shared__ int wsum[4];
    int b = blockIdx.x, t = threadIdx.x;
    int idx = b * 1024 + t * 4;
    int s = 0;
    if (idx + 3 < N) {
        int4 v = *(const int4*)(deg + idx);
        s = v.x + v.y + v.z + v.w;
    } else {
        for (int i = 0; i < 4; i++) if (idx + i < N) s += deg[idx + i];
    }
#pragma unroll
    for (int off = 32; off > 0; off >>= 1) s += __shfl_xor(s, off);
    if ((t & 63) == 0) wsum[t >> 6] = s;
    __syncthreads();
    if (t == 0) bsum[b] = wsum[0] + wsum[1] + wsum[2] + wsum[3];
}

__global__ __launch_bounds__(256) void scan_blk(const int* __restrict__ deg, const int* __restrict__ bsum,
                                                int* __restrict__ rowptr, int* __restrict__ cursor,
                                                int N, int nb, int E) {
    __shared__ int wsum[4];
    __shared__ int boff_s;
    int b = blockIdx.x, t = threadIdx.x;
    // wave 0: boff = sum of bsum[0..b)
    if (t < 64) {
        int v = (t < b && t < nb) ? bsum[t] : 0;
#pragma unroll
        for (int off = 32; off > 0; off >>= 1) v += __shfl_xor(v, off);
        if (t == 0) boff_s = v;
    }
    if (b == 0 && t == 0) rowptr[N] = E;
    int idx = b * 1024 + t * 4;
    int v0 = 0, v1 = 0, v2 = 0, v3 = 0;
    if (idx + 3 < N) {
        int4 v = *(const int4*)(deg + idx);
        v0 = v.x; v1 = v.y; v2 = v.z; v3 = v.w;
    } else if (idx < N) {
        v0 = deg[idx];
        if (idx + 1 < N) v1 = deg[idx + 1];
        if (idx + 2 < N) v2 = deg[idx + 2];
    }
    int s = v0 + v1 + v2 + v3;
    int lane = t & 63, wid = t >> 6;
    int x = s;
#pragma unroll
    for (int off = 1; off < 64; off <<= 1) {
        int y = __shfl_up(x, off);
        if (lane >= off) x += y;
    }
    if (lane == 63) wsum[wid] = x;
    __syncthreads();
    int add = boff_s;
    for (int ww = 0; ww < wid; ++ww) add += wsum[ww];
    int e0 = add + x - s;
    int e1 = e0 + v0, e2 = e1 + v1, e3 = e2 + v2;
    if (idx < N)     { rowptr[idx] = e0;     cursor[idx] = e0; }
    if (idx + 1 < N) { rowptr[idx + 1] = e1; cursor[idx + 1] = e1; }
    if (idx + 2 < N) { rowptr[idx + 2] = e2; cursor[idx + 2] = e2; }
    if (idx + 3 < N) { rowptr[idx + 3] = e3; cursor[idx + 3] = e3; }
}

// ---------------- edge scoring + CSR scatter (packed pair) ----------------
__global__ void edge_k(const int* __restrict__ src, const int* __restrict__ dst,
                       const float* __restrict__ s_src, const float* __restrict__ s_dst,
                       int* __restrict__ cursor, int2* __restrict__ csr, int E) {
    int i = blockIdx.x * blockDim.x + threadIdx.x;
    if (i >= E) return;
    int s = src[i], d = dst[i];
    float sc = s_src[s] + s_dst[d];
    float lrv = sc > 0.f ? sc : NEG_SLOPE * sc;
    float ev = __expf(-lrv);
    int pos = atomicAdd(&cursor[s], 1);
    csr[pos] = make_int2(d, __float_as_int(ev));
}

// ---------------- per-row gather SpMM (bf16 h) + div + ELU ----------------
__global__ __launch_bounds__(256) void gather_k(const unsigned short* __restrict__ hb,
                                                const int* __restrict__ rowptr,
                                                const int2* __restrict__ csr,
                                                float* __restrict__ out, int N) {
    int gt = blockIdx.x * blockDim.x + threadIdx.x;
    int w = gt >> 6;
    int lane = threadIdx.x & 63;
    if (w >= N) return;
    int s0 = rowptr[w], s1 = rowptr[w + 1];
    float a0 = 0.f, a1 = 0.f, a2 = 0.f, a3 = 0.f, rs = 0.f;
    for (int base = s0; base < s1; base += 64) {
        int cnt = min(64, s1 - base);
        int dv = 0; float ev = 0.f;
        if (lane < cnt) {
            int2 p = csr[base + lane];
            dv = p.x; ev = __int_as_float(p.y);
        }
        int jj = 0;
        for (; jj + 4 <= cnt; jj += 4) {
            int d0 = __shfl(dv, jj), d1 = __shfl(dv, jj + 1), d2 = __shfl(dv, jj + 2), d3 = __shfl(dv, jj + 3);
            float e0 = __shfl(ev, jj), e1 = __shfl(ev, jj + 1), e2 = __shfl(ev, jj + 2), e3 = __shfl(ev, jj + 3);
            ushort4 h0 = *(const ushort4*)(hb + (size_t)d0 * DOUT + lane * 4);
            ushort4 h1 = *(const ushort4*)(hb + (size_t)d1 * DOUT + lane * 4);
            ushort4 h2 = *(const ushort4*)(hb + (size_t)d2 * DOUT + lane * 4);
            ushort4 h3 = *(const ushort4*)(hb + (size_t)d3 * DOUT + lane * 4);
            a0 += e0 * bf2f(h0.x) + e1 * bf2f(h1.x) + e2 * bf2f(h2.x) + e3 * bf2f(h3.x);
            a1 += e0 * bf2f(h0.y) + e1 * bf2f(h1.y) + e2 * bf2f(h2.y) + e3 * bf2f(h3.y);
            a2 += e0 * bf2f(h0.z) + e1 * bf2f(h1.z) + e2 * bf2f(h2.z) + e3 * bf2f(h3.z);
            a3 += e0 * bf2f(h0.w) + e1 * bf2f(h1.w) + e2 * bf2f(h2.w) + e3 * bf2f(h3.w);
            rs += e0 + e1 + e2 + e3;
        }
        for (; jj < cnt; ++jj) {
            int d0 = __shfl(dv, jj);
            float e0 = __shfl(ev, jj);
            ushort4 h0 = *(const ushort4*)(hb + (size_t)d0 * DOUT + lane * 4);
            a0 += e0 * bf2f(h0.x);
            a1 += e0 * bf2f(h0.y);
            a2 += e0 * bf2f(h0.z);
            a3 += e0 * bf2f(h0.w);
            rs += e0;
        }
    }
    float inv = 1.f / rs;
    float4 v;
    v.x = a0 * inv; v.y = a1 * inv; v.z = a2 * inv; v.w = a3 * inv;
    v.x = v.x > 0.f ? v.x : __expf(v.x) - 1.f;
    v.y = v.y > 0.f ? v.y : __expf(v.y) - 1.f;
    v.z = v.z > 0.f ? v.z : __expf(v.z) - 1.f;
    v.w = v.w > 0.f ? v.w : __expf(v.w) - 1.f;
    *(float4*)(out + (size_t)w * DOUT + lane * 4) = v;
}

extern "C" void kernel_launch(void* const* d_in, const int* in_sizes, int n_in,
                              void* d_out, int out_size, void* d_ws, size_t ws_size,
                              hipStream_t stream) {
    const float* x = (const float*)d_in[0];
    const float* W = (const float*)d_in[1];
    const float* a = (const float*)d_in[2];
    const int* edge_src = (const int*)d_in[3];
    const int* edge_dst = (const int*)d_in[4];

    const int N = in_sizes[0] / DIN;
    const int E = in_sizes[3];
    const int nb = (N + 1023) / 1024;

    char* ws = (char*)d_ws;
    size_t off = 0;
    auto alloc = [&](size_t bytes) {
        void* p = ws + off;
        off += (bytes + 15) & ~(size_t)15;
        return p;
    };
    unsigned short* hb = (unsigned short*)alloc((size_t)N * DOUT * 2);
    unsigned short* Bp = (unsigned short*)alloc((size_t)DIN * DOUT * 2);
    int* rowptr = (int*)alloc((size_t)(N + 1) * 4);
    int* deg = (int*)alloc((size_t)N * 4);
    int* cursor = (int*)alloc((size_t)N * 4);
    float* s_src = (float*)alloc((size_t)N * 4);
    float* s_dst = (float*)alloc((size_t)N * 4);
    int2* csr = (int2*)alloc((size_t)E * 8);
    int* bsum = (int*)alloc((size_t)nb * 4);
    (void)ws_size;

    float* out = (float*)d_out;

    prep<<<(N + 255) / 256, 256, 0, stream>>>(W, Bp, deg, s_src, s_dst, N);
    hist_k<<<(E / 4 + 255) / 256, 256, 0, stream>>>(edge_src, deg, E);
    dim3 ggrid((N + 31) / 32, 2);
    gemm_k<<<ggrid, 64, 0, stream>>>(x, Bp, hb, a, s_src, s_dst, N);
    block_sum<<<nb, 256, 0, stream>>>(deg, bsum, N);
    scan_blk<<<nb, 256, 0, stream>>>(deg, bsum, rowptr, cursor, N, nb, E);
    edge_k<<<(E + 255) / 256, 256, 0, stream>>>(edge_src, edge_dst, s_src, s_dst,
                                                cursor, csr, E);
    gather_k<<<(N + 3) / 4, 256, 0, stream>>>(hb, rowptr, csr, out, N);
}